// Round 13
// baseline (97.135 us; speedup 1.0000x reference)
//
#include <hip/hip_runtime.h>
#include <math.h>

#define KMAX   32
#define CIN    64
#define COUT   64
#define NKERN  27
#define GPW    8          // points per wave; block = 4 waves x 8 = 32 points
#define SPAD   72         // sp_tile row stride (f16): 64 + 8 pad -> conflict-free b128
constexpr float BN_EPS = 1e-5f;

typedef _Float16 f16;
typedef _Float16 f16x2 __attribute__((ext_vector_type(2)));
typedef _Float16 f16x8 __attribute__((ext_vector_type(8)));
typedef float    f32x4 __attribute__((ext_vector_type(4)));

// ------- kernel A: cvt f32->f16, + (block 0) stats/zrow/dw-pack -------
// dwf layout (MFMA B-frag): entry i = (j*2+s)*64 + l:
//   dwf[i*8+e] = dw[s*32 + (l>>4)*8 + e][j*16 + (l&15)]
__global__ __launch_bounds__(256) void k_cvt(const float* __restrict__ in,
                                             f16* __restrict__ out,
                                             const float* __restrict__ dw,
                                             f16* __restrict__ dwf,
                                             float* __restrict__ stats,
                                             f16* __restrict__ zrow,
                                             int total4) {
    if (blockIdx.x == 0) {
        const int t = threadIdx.x;
        if (t < 128) stats[t] = 0.0f;
        if (t < CIN) zrow[t] = (f16)0.0f;
        for (int i = t; i < 512; i += 256) {
            const int j = i >> 7, s = (i >> 6) & 1, l = i & 63;
            const int col = j * 16 + (l & 15);
            const int k0  = s * 32 + ((l >> 4) * 8);
            #pragma unroll
            for (int e = 0; e < 8; ++e)
                dwf[(size_t)i * 8 + e] = (f16)dw[(k0 + e) * COUT + col];
        }
    }
    const int stride = gridDim.x * blockDim.x;
    for (int i = blockIdx.x * blockDim.x + threadIdx.x; i < total4; i += stride) {
        const float4 v = ((const float4*)in)[i];
        f16x2 a = { (f16)v.x, (f16)v.y };
        f16x2 b = { (f16)v.z, (f16)v.w };
        uint2 u;
        u.x = *(const unsigned int*)&a;
        u.y = *(const unsigned int*)&b;
        ((uint2*)out)[i] = u;
    }
}

// ------- kernel P: pack idx|flt (validity resolved) + 1/cnt -----------
// idx fits 17 bits (zrow = 65536), flt < 27 in bits 17..21.
__global__ __launch_bounds__(256) void k_pack(
    const int* __restrict__ nn_count,
    const int* __restrict__ nn_index,
    const int* __restrict__ filt_index,
    int*       __restrict__ packed,
    float*     __restrict__ invc,
    int total_q, int zrowIdx) {
    const int t = blockIdx.x * 256 + threadIdx.x;
    if (t >= total_q) return;
    const int n = t >> 3, q = t & 7;
    const int cnt = nn_count[n];
    const int4 ni = ((const int4*)nn_index)[t];
    const int4 fi = ((const int4*)filt_index)[t];
    const int k0 = q * 4;
    int4 pk;
    pk.x = ((k0 + 0) < cnt ? ni.x : zrowIdx) | (fi.x << 17);
    pk.y = ((k0 + 1) < cnt ? ni.y : zrowIdx) | (fi.y << 17);
    pk.z = ((k0 + 2) < cnt ? ni.z : zrowIdx) | (fi.z << 17);
    pk.w = ((k0 + 3) < cnt ? ni.w : zrowIdx) | (fi.w << 17);
    ((int4*)packed)[t] = pk;
    if (q == 0) invc[n] = 1.0f / (float)cnt;
}

// ------- kernel G: gather + spatial filter + MFMA matmul epilogue -----
// Gather loop identical to R12's 49us version; sp lands in padded LDS.
// After one barrier, each wave runs the 16x64 @ 64x64 MFMA for its
// 16-column tile over both 16-row tiles, writes pre-BN x to out, and
// accumulates BN stats (1 atomic pair per column per block).
__global__ __launch_bounds__(256, 4) void k_gather(
    const f16*   __restrict__ gh,          // f16[(N+1),64], row N = zeros
    const float* __restrict__ sw,          // [27,64]
    const int*   __restrict__ packed,      // [N,32] idx|(flt<<17)
    const float* __restrict__ invc,        // [N] 1/cnt
    const f16*   __restrict__ dwf,         // packed B-frags
    const float* __restrict__ bias,        // [1,64]
    float*       __restrict__ out,         // [N,64] pre-BN x
    float*       __restrict__ stats)       // [128]
{
    __shared__ float sw_lds[NKERN * CIN];      // 6.75 KB
    __shared__ f16   sp_tile[32][SPAD];        // 4.5 KB, padded
    const int tid = threadIdx.x;
    for (int i = tid; i < NKERN * CIN; i += 256) sw_lds[i] = sw[i];
    __syncthreads();

    const int wave = tid >> 6;
    const int lane = tid & 63;
    const int base = blockIdx.x * (4 * GPW) + wave * GPW;

    for (int p = 0; p < GPW; ++p) {
        const int n = base + p;
        const int4* __restrict__ pk4 = (const int4*)(packed + (size_t)n * KMAX);

        int pk[32];
        #pragma unroll
        for (int q = 0; q < 8; ++q) *(int4*)&pk[4 * q] = pk4[q];
        const float ic = invc[n];

        f16 g[32];
        #pragma unroll
        for (int k = 0; k < 32; ++k)           // 32 independent gathers
            g[k] = gh[(size_t)(pk[k] & 0x1FFFF) * CIN + lane];

        float a0 = 0.f, a1 = 0.f, a2 = 0.f, a3 = 0.f;
        #pragma unroll
        for (int k = 0; k < 32; ++k) {
            float& a = (k & 3) == 0 ? a0 : (k & 3) == 1 ? a1
                     : (k & 3) == 2 ? a2 : a3;
            a = fmaf((float)g[k], sw_lds[(pk[k] >> 17) * CIN + lane], a);
        }
        sp_tile[wave * GPW + p][lane] = (f16)((((a0 + a1) + (a2 + a3))) * ic);
    }

    __syncthreads();

    // ---- MFMA epilogue: wave j = column tile j ----
    const f16x8* dwf8 = (const f16x8*)dwf;
    const f16x8 b0 = dwf8[(wave * 2 + 0) * 64 + lane];
    const f16x8 b1 = dwf8[(wave * 2 + 1) * 64 + lane];
    const float bias_c = bias[wave * 16 + (lane & 15)];
    const int r0g = blockIdx.x * 32;
    float sum = 0.f, sq = 0.f;

    #pragma unroll
    for (int t = 0; t < 2; ++t) {
        const f16* arow = &sp_tile[t * 16 + (lane & 15)][(lane >> 4) * 8];
        const f16x8 a0 = *(const f16x8*)arow;          // ds_read_b128
        const f16x8 a1 = *(const f16x8*)(arow + 32);   // ds_read_b128
        f32x4 acc = {0.f, 0.f, 0.f, 0.f};
        acc = __builtin_amdgcn_mfma_f32_16x16x32_f16(a0, b0, acc, 0, 0, 0);
        acc = __builtin_amdgcn_mfma_f32_16x16x32_f16(a1, b1, acc, 0, 0, 0);
        #pragma unroll
        for (int r = 0; r < 4; ++r) {
            const float x = fmaxf(acc[r] + bias_c, 0.0f);
            out[(size_t)(r0g + t * 16 + (lane >> 4) * 4 + r) * COUT
                + wave * 16 + (lane & 15)] = x;
            sum += x;
            sq  += x * x;
        }
    }

    sum += __shfl_xor(sum, 16); sum += __shfl_xor(sum, 32);
    sq  += __shfl_xor(sq, 16);  sq  += __shfl_xor(sq, 32);
    if (lane < 16) {
        atomicAdd(&stats[wave * 16 + lane], sum);
        atomicAdd(&stats[COUT + wave * 16 + lane], sq);
    }
}

// ---------------- kernel 2: finalize BN scale/shift -------------------
__global__ void k_finalize(const float* __restrict__ stats,
                           const float* __restrict__ gamma,
                           const float* __restrict__ beta,
                           float* __restrict__ sc_sh, float invN) {
    const int j = threadIdx.x;               // 64 threads
    const float mean = stats[j] * invN;
    const float var  = stats[COUT + j] * invN - mean * mean;
    const float s    = gamma[j] * rsqrtf(var + BN_EPS);
    sc_sh[j]        = s;
    sc_sh[COUT + j] = beta[j] - mean * s;
}

// ---------------- kernel 3: apply BN in place on d_out ----------------
__global__ __launch_bounds__(256) void k_apply(float* __restrict__ x,
                                               const float* __restrict__ sc_sh,
                                               int total4) {
    __shared__ float s[COUT], sh[COUT];
    if (threadIdx.x < COUT) {
        s[threadIdx.x]  = sc_sh[threadIdx.x];
        sh[threadIdx.x] = sc_sh[COUT + threadIdx.x];
    }
    __syncthreads();
    const int stride = gridDim.x * blockDim.x;
    for (int idx = blockIdx.x * blockDim.x + threadIdx.x; idx < total4; idx += stride) {
        float4 v = ((const float4*)x)[idx];
        const int j = (idx * 4) & (COUT - 1);
        v.x = fmaf(v.x, s[j],     sh[j]);
        v.y = fmaf(v.y, s[j + 1], sh[j + 1]);
        v.z = fmaf(v.z, s[j + 2], sh[j + 2]);
        v.w = fmaf(v.w, s[j + 3], sh[j + 3]);
        ((float4*)x)[idx] = v;
    }
}

extern "C" void kernel_launch(void* const* d_in, const int* in_sizes, int n_in,
                              void* d_out, int out_size, void* d_ws, size_t ws_size,
                              hipStream_t stream) {
    const float* inputs     = (const float*)d_in[0];
    const float* sw         = (const float*)d_in[1];
    const float* dw         = (const float*)d_in[2];
    const float* bias       = (const float*)d_in[3];
    const float* gamma      = (const float*)d_in[4];
    const float* beta       = (const float*)d_in[5];
    const int*   nn_count   = (const int*)d_in[6];
    const int*   nn_index   = (const int*)d_in[7];
    const int*   filt_index = (const int*)d_in[8];

    const int N = in_sizes[0] / CIN;           // 65536
    float* out   = (float*)d_out;

    // ws: stats(128f) | sc_sh(128f) | in_h((N+1)*64 f16) | dwf(4096 f16)
    //     | packed(N*32 int) | invc(N f32)
    float* stats  = (float*)d_ws;
    float* sc_sh  = (float*)d_ws + 128;
    f16*   in_h   = (f16*)((float*)d_ws + 256);
    f16*   dwf    = in_h + (size_t)(N + 1) * CIN;
    int*   packed = (int*)(dwf + 4096);
    float* invc   = (float*)(packed + (size_t)N * KMAX);

    k_cvt<<<2048, 256, 0, stream>>>(inputs, in_h, dw, dwf, stats,
                                    in_h + (size_t)N * CIN, N * CIN / 4);

    const int total_q = N * (KMAX / 4);        // 524288 int4 groups
    k_pack<<<(total_q + 255) / 256, 256, 0, stream>>>(
        nn_count, nn_index, filt_index, packed, invc, total_q, N);

    k_gather<<<N / (4 * GPW), 256, 0, stream>>>(
        in_h, sw, packed, invc, dwf, bias, out, stats);

    k_finalize<<<1, COUT, 0, stream>>>(stats, gamma, beta, sc_sh, 1.0f / (float)N);

    k_apply<<<2048, 256, 0, stream>>>(out, sc_sh, N * COUT / 4);
}

// Round 14
// 81.919 us; speedup vs baseline: 1.1857x; 1.1857x over previous
//
#include <hip/hip_runtime.h>
#include <math.h>

#define KMAX   32
#define CIN    64
#define COUT   64
#define NKERN  27
#define GPW    8          // points per wave, gather kernel
#define MMT    2          // 16-row tiles per wave, matmul kernels
constexpr float BN_EPS = 1e-5f;

typedef _Float16 f16;
typedef _Float16 f16x2 __attribute__((ext_vector_type(2)));
typedef _Float16 f16x8 __attribute__((ext_vector_type(8)));
typedef float    f32x4 __attribute__((ext_vector_type(4)));

// ------- kernel A: cvt f32->f16  ||  pack indices (block-split) -------
// blocks [0, cvtBlocks): cvt grid-stride; blocks [cvtBlocks, +packBlocks):
// pack idx/flt. Block 0 additionally inits stats, zeros-row, dwf B-frags.
// packed pk = (idx<<7) | (flt<<24):  gather byte-off = (pk & 0xFFFFFF),
//                                    sw LDS byte-off = (pk>>16) & 0x1F00.
__global__ __launch_bounds__(256) void k_cvtpack(
    const float* __restrict__ in,          // [N*64] f32
    f16*         __restrict__ out,         // [(N+1)*64] f16
    const float* __restrict__ dw,
    f16*         __restrict__ dwf,
    float*       __restrict__ stats,
    const int*   __restrict__ nn_count,
    const int*   __restrict__ nn_index,
    const int*   __restrict__ filt_index,
    int*         __restrict__ packed,
    float*       __restrict__ invc,
    int total4, int cvtBlocks, int total_q, int zrowIdx)
{
    const int bid = blockIdx.x;
    if (bid == 0) {
        const int t = threadIdx.x;
        if (t < 128) stats[t] = 0.0f;
        if (t < CIN) out[(size_t)zrowIdx * CIN + t] = (f16)0.0f;   // zeros row
        for (int i = t; i < 512; i += 256) {       // dwf B-frag pack
            const int j = i >> 7, s = (i >> 6) & 1, l = i & 63;
            const int col = j * 16 + (l & 15);
            const int k0  = s * 32 + ((l >> 4) * 8);
            #pragma unroll
            for (int e = 0; e < 8; ++e)
                dwf[(size_t)i * 8 + e] = (f16)dw[(k0 + e) * COUT + col];
        }
    }
    if (bid < cvtBlocks) {
        const int stride = cvtBlocks * 256;
        for (int i = bid * 256 + threadIdx.x; i < total4; i += stride) {
            const float4 v = ((const float4*)in)[i];
            f16x2 a = { (f16)v.x, (f16)v.y };
            f16x2 b = { (f16)v.z, (f16)v.w };
            uint2 u;
            u.x = *(const unsigned int*)&a;
            u.y = *(const unsigned int*)&b;
            ((uint2*)out)[i] = u;
        }
    } else {
        const int t = (bid - cvtBlocks) * 256 + threadIdx.x;
        if (t < total_q) {
            const int n = t >> 3, q = t & 7;
            const int cnt = nn_count[n];
            const int4 ni = ((const int4*)nn_index)[t];
            const int4 fi = ((const int4*)filt_index)[t];
            const int k0 = q * 4;
            int4 pk;
            pk.x = (((k0 + 0) < cnt ? ni.x : zrowIdx) << 7) | (fi.x << 24);
            pk.y = (((k0 + 1) < cnt ? ni.y : zrowIdx) << 7) | (fi.y << 24);
            pk.z = (((k0 + 2) < cnt ? ni.z : zrowIdx) << 7) | (fi.z << 24);
            pk.w = (((k0 + 3) < cnt ? ni.w : zrowIdx) << 7) | (fi.w << 24);
            ((int4*)packed)[t] = pk;
            if (q == 0) invc[n] = 1.0f / (float)cnt;
        }
    }
}

// ------- kernel G: gather + spatial filter (packed byte-offsets) ------
__global__ __launch_bounds__(256, 8) void k_gather(
    const f16*   __restrict__ gh,          // f16[(N+1),64], row N = zeros
    const float* __restrict__ sw,          // [27,64]
    const int*   __restrict__ packed,      // [N,32] (idx<<7)|(flt<<24)
    const float* __restrict__ invc,        // [N] 1/cnt
    f16*         __restrict__ sp)          // [N,64] out
{
    __shared__ float sw_lds[NKERN * CIN];  // 6.75 KB
    const int tid = threadIdx.x;
    for (int i = tid; i < NKERN * CIN; i += 256) sw_lds[i] = sw[i];
    __syncthreads();

    const int wave = tid >> 6;
    const int lane = tid & 63;
    const int base = blockIdx.x * (4 * GPW) + wave * GPW;
    const unsigned lane2 = lane * 2;       // byte off within gather row
    const unsigned lane4 = lane * 4;       // byte off within sw row
    const char* __restrict__ ghb = (const char*)gh;
    const char* __restrict__ swb = (const char*)sw_lds;

    for (int p = 0; p < GPW; ++p) {
        const int n = base + p;
        const int4* __restrict__ pk4 = (const int4*)(packed + (size_t)n * KMAX);

        int pk[32];
        #pragma unroll
        for (int q = 0; q < 8; ++q) *(int4*)&pk[4 * q] = pk4[q];
        const float ic = invc[n];

        f16 g[32];
        #pragma unroll
        for (int k = 0; k < 32; ++k)           // 32 independent gathers
            g[k] = *(const f16*)(ghb + (((unsigned)pk[k] & 0xFFFFFFu) + lane2));

        float a0 = 0.f, a1 = 0.f, a2 = 0.f, a3 = 0.f;
        #pragma unroll
        for (int k = 0; k < 32; ++k) {
            const float wv = *(const float*)(swb + ((((unsigned)pk[k] >> 16) & 0x1F00u) + lane4));
            float& a = (k & 3) == 0 ? a0 : (k & 3) == 1 ? a1
                     : (k & 3) == 2 ? a2 : a3;
            a = fmaf((float)g[k], wv, a);
        }
        sp[(size_t)n * CIN + lane] = (f16)((((a0 + a1) + (a2 + a3))) * ic);
    }
}

// ---------------- MFMA matmul body shared by both passes --------------
// A-frag: lane holds sp[r0 + (l&15)][(l>>4)*8 + e (+32)]  (contiguous f16x8)
// C-frag: row = (l>>4)*4 + r, col = j*16 + (l&15)          (m89-verified)
#define MM_LOAD_AB(r0)                                                        \
    const f16* arow = sp + (size_t)((r0) + (lane & 15)) * CIN + ((lane >> 4) * 8); \
    const f16x8 a0 = *(const f16x8*)(arow);                                   \
    const f16x8 a1 = *(const f16x8*)(arow + 32);

// ---------------- kernel M1: MFMA matmul + relu -> BN stats -----------
__global__ __launch_bounds__(256) void k_mm_stats(
    const f16*   __restrict__ sp,          // [N,64]
    const f16*   __restrict__ dwf,         // packed B-frags
    const float* __restrict__ bias,        // [1,64]
    float*       __restrict__ stats)       // [128]
{
    __shared__ float rsum[4][4][16], rsq[4][4][16];
    const int tid = threadIdx.x;
    const int wave = tid >> 6, lane = tid & 63;

    const f16x8* dwf8 = (const f16x8*)dwf;
    f16x8 b[4][2];
    #pragma unroll
    for (int j = 0; j < 4; ++j) {
        b[j][0] = dwf8[(j * 2 + 0) * 64 + lane];
        b[j][1] = dwf8[(j * 2 + 1) * 64 + lane];
    }
    float bias_c[4];
    #pragma unroll
    for (int j = 0; j < 4; ++j) bias_c[j] = bias[j * 16 + (lane & 15)];

    float sum[4] = {0, 0, 0, 0}, sq[4] = {0, 0, 0, 0};
    const int rowbase = (blockIdx.x * 4 + wave) * (MMT * 16);

    for (int t = 0; t < MMT; ++t) {
        MM_LOAD_AB(rowbase + t * 16)
        #pragma unroll
        for (int j = 0; j < 4; ++j) {
            f32x4 acc = {0.f, 0.f, 0.f, 0.f};
            acc = __builtin_amdgcn_mfma_f32_16x16x32_f16(a0, b[j][0], acc, 0, 0, 0);
            acc = __builtin_amdgcn_mfma_f32_16x16x32_f16(a1, b[j][1], acc, 0, 0, 0);
            #pragma unroll
            for (int r = 0; r < 4; ++r) {
                const float x = fmaxf(acc[r] + bias_c[j], 0.0f);
                sum[j] += x;
                sq[j]  += x * x;
            }
        }
    }

    #pragma unroll
    for (int j = 0; j < 4; ++j) {
        sum[j] += __shfl_xor(sum[j], 16); sum[j] += __shfl_xor(sum[j], 32);
        sq[j]  += __shfl_xor(sq[j], 16);  sq[j]  += __shfl_xor(sq[j], 32);
    }
    if (lane < 16) {
        #pragma unroll
        for (int j = 0; j < 4; ++j) {
            rsum[wave][j][lane] = sum[j];
            rsq[wave][j][lane]  = sq[j];
        }
    }
    __syncthreads();
    if (wave == 0 && lane < 16) {
        #pragma unroll
        for (int j = 0; j < 4; ++j) {
            const float s = rsum[0][j][lane] + rsum[1][j][lane]
                          + rsum[2][j][lane] + rsum[3][j][lane];
            const float q = rsq[0][j][lane] + rsq[1][j][lane]
                          + rsq[2][j][lane] + rsq[3][j][lane];
            atomicAdd(&stats[j * 16 + lane], s);
            atomicAdd(&stats[COUT + j * 16 + lane], q);
        }
    }
}

// ---------------- kernel 2: finalize BN scale/shift -------------------
__global__ void k_finalize(const float* __restrict__ stats,
                           const float* __restrict__ gamma,
                           const float* __restrict__ beta,
                           float* __restrict__ sc_sh, float invN) {
    const int j = threadIdx.x;               // 64 threads
    const float mean = stats[j] * invN;
    const float var  = stats[COUT + j] * invN - mean * mean;
    const float s    = gamma[j] * rsqrtf(var + BN_EPS);
    sc_sh[j]        = s;
    sc_sh[COUT + j] = beta[j] - mean * s;
}

// ---------------- kernel M2: MFMA matmul + relu + BN -> d_out ---------
__global__ __launch_bounds__(256) void k_mm_out(
    const f16*   __restrict__ sp,          // [N,64]
    const f16*   __restrict__ dwf,         // packed B-frags
    const float* __restrict__ bias,        // [1,64]
    const float* __restrict__ sc_sh,       // [128]
    float*       __restrict__ out)         // [N,64]
{
    const int tid = threadIdx.x;
    const int wave = tid >> 6, lane = tid & 63;

    const f16x8* dwf8 = (const f16x8*)dwf;
    f16x8 b[4][2];
    #pragma unroll
    for (int j = 0; j < 4; ++j) {
        b[j][0] = dwf8[(j * 2 + 0) * 64 + lane];
        b[j][1] = dwf8[(j * 2 + 1) * 64 + lane];
    }
    float bias_c[4], sc[4], sh[4];
    #pragma unroll
    for (int j = 0; j < 4; ++j) {
        const int c = j * 16 + (lane & 15);
        bias_c[j] = bias[c];
        sc[j]     = sc_sh[c];
        sh[j]     = sc_sh[COUT + c];
    }

    const int rowbase = (blockIdx.x * 4 + wave) * (MMT * 16);
    for (int t = 0; t < MMT; ++t) {
        const int r0 = rowbase + t * 16;
        MM_LOAD_AB(r0)
        #pragma unroll
        for (int j = 0; j < 4; ++j) {
            f32x4 acc = {0.f, 0.f, 0.f, 0.f};
            acc = __builtin_amdgcn_mfma_f32_16x16x32_f16(a0, b[j][0], acc, 0, 0, 0);
            acc = __builtin_amdgcn_mfma_f32_16x16x32_f16(a1, b[j][1], acc, 0, 0, 0);
            #pragma unroll
            for (int r = 0; r < 4; ++r) {
                const float x = fmaxf(acc[r] + bias_c[j], 0.0f);
                out[(size_t)(r0 + (lane >> 4) * 4 + r) * COUT + j * 16 + (lane & 15)]
                    = fmaf(x, sc[j], sh[j]);
            }
        }
    }
}

extern "C" void kernel_launch(void* const* d_in, const int* in_sizes, int n_in,
                              void* d_out, int out_size, void* d_ws, size_t ws_size,
                              hipStream_t stream) {
    const float* inputs     = (const float*)d_in[0];
    const float* sw         = (const float*)d_in[1];
    const float* dw         = (const float*)d_in[2];
    const float* bias       = (const float*)d_in[3];
    const float* gamma      = (const float*)d_in[4];
    const float* beta       = (const float*)d_in[5];
    const int*   nn_count   = (const int*)d_in[6];
    const int*   nn_index   = (const int*)d_in[7];
    const int*   filt_index = (const int*)d_in[8];

    const int N = in_sizes[0] / CIN;           // 65536
    float* out   = (float*)d_out;

    // ws: stats(128f) | sc_sh(128f) | in_h((N+1)*64 f16) | sp(N*64 f16)
    //     | dwf(4096 f16) | packed(N*32 int) | invc(N f32)
    float* stats  = (float*)d_ws;
    float* sc_sh  = (float*)d_ws + 128;
    f16*   in_h   = (f16*)((float*)d_ws + 256);
    f16*   spb    = in_h + (size_t)(N + 1) * CIN;
    f16*   dwf    = spb + (size_t)N * CIN;
    int*   packed = (int*)(dwf + 4096);
    float* invc   = (float*)(packed + (size_t)N * KMAX);

    const int total4    = N * CIN / 4;         // 1048576 float4 groups
    const int cvtBlocks = 2048;
    const int total_q   = N * (KMAX / 4);      // 524288 int4 groups
    const int packBlocks = (total_q + 255) / 256;

    k_cvtpack<<<cvtBlocks + packBlocks, 256, 0, stream>>>(
        inputs, in_h, dw, dwf, stats,
        nn_count, nn_index, filt_index, packed, invc,
        total4, cvtBlocks, total_q, N);

    k_gather<<<N / (4 * GPW), 256, 0, stream>>>(in_h, sw, packed, invc, spb);

    k_mm_stats<<<N / (4 * MMT * 16), 256, 0, stream>>>(spb, dwf, bias, stats);
    k_finalize<<<1, COUT, 0, stream>>>(stats, gamma, beta, sc_sh, 1.0f / (float)N);
    k_mm_out<<<N / (4 * MMT * 16), 256, 0, stream>>>(spb, dwf, bias, sc_sh, out);
}